// Round 5
// baseline (1132.739 us; speedup 1.0000x reference)
//
#include <hip/hip_runtime.h>

#define IN_DIM 256
#define HID 128
#define CAP 48        // bucket capacity per node; P(Poisson(16) >= 48) ~ 1e-30
#define RANGE 512     // nodes per bin (dst>>9); LDS adjacency 512*48*4 = 96KB
#define RSH 9
#define MAXB 256      // max bins supported (N <= 131072; also s fits 17 bits)
#define CAPB 10240    // per-bin edge capacity (~8163 avg, 25% slack)
#define CHUNK 4096    // edges per bin_k workgroup (256 thr * 16)

using short8 = __attribute__((ext_vector_type(8))) short;
using f32x4  = __attribute__((ext_vector_type(4))) float;

// ---------------------------------------------------------------------------
// bf16 helpers (RNE round, bit-level)
// ---------------------------------------------------------------------------
__device__ __forceinline__ unsigned short f2bf(float x) {
    unsigned int u = __float_as_uint(x);
    u += 0x7fffu + ((u >> 16) & 1u);
    return (unsigned short)(u >> 16);
}
__device__ __forceinline__ float bf2f(unsigned short b) {
    return __uint_as_float((unsigned int)b << 16);
}

// ---------------------------------------------------------------------------
// int64-vs-int32 edge storage detect for all 3 graphs in one launch
// ---------------------------------------------------------------------------
__global__ void detect3_k(const int* __restrict__ a, const int* __restrict__ b,
                          const int* __restrict__ c, int n_check,
                          int* __restrict__ modes) {
    const int* e = (blockIdx.x == 0) ? a : (blockIdx.x == 1) ? b : c;
    __shared__ int any_nz;
    if (threadIdx.x == 0) any_nz = 0;
    __syncthreads();
    for (int i = threadIdx.x; i < n_check; i += blockDim.x) {
        if (e[2 * i + 1] != 0) atomicOr(&any_nz, 1);
    }
    __syncthreads();
    if (threadIdx.x == 0) modes[blockIdx.x] = any_nz ? 0 : 1;
}

// ---------------------------------------------------------------------------
// One-time weight prep: W[K][128] fp32 -> transposed bf16 hi/lo planes
// W*T[col][k].
// ---------------------------------------------------------------------------
__global__ __launch_bounds__(256) void prep_w_k(const float* __restrict__ W0,
                                                const float* __restrict__ W1,
                                                unsigned short* __restrict__ W0hiT,
                                                unsigned short* __restrict__ W0loT,
                                                unsigned short* __restrict__ W1hiT,
                                                unsigned short* __restrict__ W1loT) {
    int gid = blockIdx.x * 256 + threadIdx.x;
    if (gid < IN_DIM * HID) {
        int k = gid >> 7, c = gid & 127;
        float v = W0[gid];
        unsigned short h = f2bf(v), l = f2bf(v - bf2f(h));
        W0hiT[(size_t)c * IN_DIM + k] = h;
        W0loT[(size_t)c * IN_DIM + k] = l;
    } else if (gid < IN_DIM * HID + HID * HID) {
        int g2 = gid - IN_DIM * HID;
        int k = g2 >> 7, c = g2 & 127;
        float v = W1[g2];
        unsigned short h = f2bf(v), l = f2bf(v - bf2f(h));
        W1hiT[(size_t)c * HID + k] = h;
        W1loT[(size_t)c * HID + k] = l;
    }
}

// ---------------------------------------------------------------------------
// Pass 1: radix-bin edges by dst>>RSH (payload pack: s | d_local<<17) and by
// src>>RSH (payload: s_local ushort). Replaces 3.2M global atomics + 1.6M
// random 4B stores with LDS histograms + ~150K global atomics + clustered
// appends (R3: killed the 143us preprocess fabric-scatter bottleneck).
// ---------------------------------------------------------------------------
__global__ __launch_bounds__(256) void bin_k(const int* __restrict__ e32, int E,
                                             const int* __restrict__ mode_p,
                                             int* __restrict__ binCntD,
                                             int* __restrict__ binCntS,
                                             unsigned int* __restrict__ binBufD,
                                             unsigned short* __restrict__ binBufS,
                                             int B) {
    __shared__ int hcD[MAXB], hcS[MAXB];
    __shared__ int baseD[MAXB], baseS[MAXB];
    const int t = threadIdx.x;
    for (int i = t; i < B; i += 256) { hcD[i] = 0; hcS[i] = 0; }
    __syncthreads();

    int s[16], d[16];
    const long long e0 = (long long)blockIdx.x * CHUNK;
    const int mode = *mode_p;

    if (mode) {  // int64 storage, values fit in low word
        const long long* __restrict__ s64 = (const long long*)e32;
        const long long* __restrict__ d64 = s64 + E;
#pragma unroll
        for (int j = 0; j < 16; ++j) {
            long long idx = e0 + j * 256 + t;
            if (idx < E) { s[j] = (int)s64[idx]; d[j] = (int)d64[idx]; }
            else         { s[j] = -1; d[j] = -1; }
        }
    } else {     // int32 storage
        const int* __restrict__ s32 = e32;
        const int* __restrict__ d32 = e32 + E;
#pragma unroll
        for (int j = 0; j < 16; ++j) {
            long long idx = e0 + j * 256 + t;
            if (idx < E) { s[j] = s32[idx]; d[j] = d32[idx]; }
            else         { s[j] = -1; d[j] = -1; }
        }
    }

    // count
#pragma unroll
    for (int j = 0; j < 16; ++j) {
        if (d[j] >= 0) {
            atomicAdd(&hcD[d[j] >> RSH], 1);
            atomicAdd(&hcS[s[j] >> RSH], 1);
        }
    }
    __syncthreads();

    // reserve global space per bin; reset hc for reuse as local offsets
    for (int i = t; i < B; i += 256) {
        int c = hcD[i];
        baseD[i] = c ? atomicAdd(&binCntD[i], c) : 0;
        hcD[i] = 0;
        c = hcS[i];
        baseS[i] = c ? atomicAdd(&binCntS[i], c) : 0;
        hcS[i] = 0;
    }
    __syncthreads();

    // place
#pragma unroll
    for (int j = 0; j < 16; ++j) {
        if (d[j] >= 0) {
            int bD = d[j] >> RSH;
            int p = atomicAdd(&hcD[bD], 1) + baseD[bD];
            if (p < CAPB)
                binBufD[(size_t)bD * CAPB + p] =
                    (unsigned int)s[j] | ((unsigned int)(d[j] & (RANGE - 1)) << 17);
            int bS = s[j] >> RSH;
            int q = atomicAdd(&hcS[bS], 1) + baseS[bS];
            if (q < CAPB)
                binBufS[(size_t)bS * CAPB + q] = (unsigned short)(s[j] & (RANGE - 1));
        }
    }
}

// ---------------------------------------------------------------------------
// Pass 2: blocks [0,B) build dst-adjacency in LDS (atomics at LDS speed),
// then stream bucket rows + true cnt out coalesced. Blocks [B,2B) histogram
// src-bins in LDS and write deg_out coalesced.
// Writes cnt/deg_out for ALL nodes -> no global memset needed for them.
// ---------------------------------------------------------------------------
__global__ __launch_bounds__(256) void build_k(const int* __restrict__ binCntD,
                                               const int* __restrict__ binCntS,
                                               const unsigned int* __restrict__ binBufD,
                                               const unsigned short* __restrict__ binBufS,
                                               int* __restrict__ bucket,
                                               int* __restrict__ cnt,
                                               int* __restrict__ deg_out,
                                               int B, int N) {
    __shared__ int lcnt[RANGE];
    __shared__ int lbuf[RANGE * CAP];   // 96KB
    const int t = threadIdx.x;

    if ((int)blockIdx.x < B) {
        const int bin = blockIdx.x;
        for (int i = t; i < RANGE; i += 256) lcnt[i] = 0;
        __syncthreads();
        const int nE = min(binCntD[bin], CAPB);
        const unsigned int* __restrict__ src = binBufD + (size_t)bin * CAPB;
        for (int i = t; i < nE; i += 256) {
            unsigned int v = src[i];
            int dl = v >> 17;
            int p = atomicAdd(&lcnt[dl], 1);
            if (p < CAP) lbuf[dl * CAP + p] = (int)(v & 0x1FFFFu);
        }
        __syncthreads();
        const int node0 = bin * RANGE;
        const int nn = min(RANGE, N - node0);
        for (int i = t; i < nn; i += 256) cnt[node0 + i] = lcnt[i];
        for (int i = t; i < nn * CAP; i += 256)
            bucket[(size_t)node0 * CAP + i] = lbuf[i];
    } else {
        const int bin = blockIdx.x - B;
        for (int i = t; i < RANGE; i += 256) lcnt[i] = 0;
        __syncthreads();
        const int nE = min(binCntS[bin], CAPB);
        const unsigned short* __restrict__ src = binBufS + (size_t)bin * CAPB;
        for (int i = t; i < nE; i += 256) atomicAdd(&lcnt[src[i]], 1);
        __syncthreads();
        const int node0 = bin * RANGE;
        const int nn = min(RANGE, N - node0);
        for (int i = t; i < nn; i += 256) deg_out[node0 + i] = lcnt[i];
    }
}

// ---------------------------------------------------------------------------
// bf16-split MFMA GEMM v3:
//   Hout[row][0:128] = bf16( (X[row][0:K] @ W[K][128]) * clip(deg,1)^-1/2 )
// R4 lesson: v2's B fragments were loaded from global per K-step and consumed
// immediately -> wave stalls on L2 latency every step (gemm stuck ~80us).
// v3: B fragments register-prefetched one step ahead (issued at top of step s,
// consumed in step s+1; register dest -> barrier does NOT force vmcnt(0)),
// loop unrolled x2 with named reg sets so all indexing is compile-time.
// As double-buffered via register prefetch as before; 1 barrier/step.
// MFMA order identical to v2 -> bitwise-same results.
// ---------------------------------------------------------------------------
__global__ __launch_bounds__(256) void gemm_v3_k(const float* __restrict__ X,
                                                 const unsigned short* __restrict__ BhiT,
                                                 const unsigned short* __restrict__ BloT,
                                                 const int* __restrict__ deg,
                                                 unsigned short* __restrict__ Hout,
                                                 int M, int K) {
    __shared__ __align__(16) unsigned short As[2][2][128 * 32];  // [buf][hi/lo]

    const int tid = threadIdx.x;
    const int lane = tid & 63;
    const int w = tid >> 6;
    const int wr = w >> 1, wc = w & 1;
    const int bm = blockIdx.x * 128;
    const int l15 = lane & 15, l4 = lane >> 4;
    const int r0 = tid >> 3;   // staging row base (this thread covers r0+32i)
    const int kq = tid & 7;    // float4 slot within the 32-wide k panel

    f32x4 acc[4][4];
#pragma unroll
    for (int m = 0; m < 4; ++m)
#pragma unroll
        for (int n = 0; n < 4; ++n) acc[m][n] = (f32x4){0.f, 0.f, 0.f, 0.f};

    float4 pf[4];
    short8 bh0[4], bl0[4], bh1[4], bl1[4];

#define LOADT(k0)                                                              \
    {                                                                          \
        _Pragma("unroll")                                                      \
        for (int i = 0; i < 4; ++i) {                                          \
            int r = r0 + i * 32;                                               \
            pf[i] = make_float4(0.f, 0.f, 0.f, 0.f);                           \
            if (bm + r < M)                                                    \
                pf[i] = *(const float4*)&X[(size_t)(bm + r) * K + (k0) + kq * 4]; \
        }                                                                      \
    }

#define STORET(buf)                                                            \
    {                                                                          \
        _Pragma("unroll")                                                      \
        for (int i = 0; i < 4; ++i) {                                          \
            int r = r0 + i * 32;                                               \
            ushort4 h, l;                                                      \
            h.x = f2bf(pf[i].x); l.x = f2bf(pf[i].x - bf2f(h.x));              \
            h.y = f2bf(pf[i].y); l.y = f2bf(pf[i].y - bf2f(h.y));              \
            h.z = f2bf(pf[i].z); l.z = f2bf(pf[i].z - bf2f(h.z));              \
            h.w = f2bf(pf[i].w); l.w = f2bf(pf[i].w - bf2f(h.w));              \
            *(ushort4*)&As[buf][0][r * 32 + kq * 4] = h;                       \
            *(ushort4*)&As[buf][1][r * 32 + kq * 4] = l;                       \
        }                                                                      \
    }

#define LOADB(s, BH, BL)                                                       \
    {                                                                          \
        const int kb = ((s) << 5) + l4 * 8;                                    \
        _Pragma("unroll")                                                      \
        for (int n = 0; n < 4; ++n) {                                          \
            int col = wc * 64 + n * 16 + l15;                                  \
            BH[n] = *(const short8*)&BhiT[(size_t)col * K + kb];               \
            BL[n] = *(const short8*)&BloT[(size_t)col * K + kb];               \
        }                                                                      \
    }

#define DOMFMA(buf, BH, BL)                                                    \
    {                                                                          \
        short8 ah[4], al[4];                                                   \
        _Pragma("unroll")                                                      \
        for (int m = 0; m < 4; ++m) {                                          \
            int row = wr * 64 + m * 16 + l15;                                  \
            ah[m] = *(const short8*)&As[buf][0][row * 32 + l4 * 8];            \
            al[m] = *(const short8*)&As[buf][1][row * 32 + l4 * 8];            \
        }                                                                      \
        _Pragma("unroll")                                                      \
        for (int m = 0; m < 4; ++m)                                            \
            _Pragma("unroll")                                                  \
            for (int n = 0; n < 4; ++n) {                                      \
                acc[m][n] = __builtin_amdgcn_mfma_f32_16x16x32_bf16(ah[m], BH[n], acc[m][n], 0, 0, 0); \
                acc[m][n] = __builtin_amdgcn_mfma_f32_16x16x32_bf16(al[m], BH[n], acc[m][n], 0, 0, 0); \
                acc[m][n] = __builtin_amdgcn_mfma_f32_16x16x32_bf16(ah[m], BL[n], acc[m][n], 0, 0, 0); \
            }                                                                  \
    }

    // prologue: stage tile 0, preload B fragments for step 0
    LOADT(0);
    STORET(0);
    LOADB(0, bh0, bl0);
    __syncthreads();

    const int NS = K >> 5;
    for (int s = 0; s < NS; s += 2) {
        // ---- step s (reads As[0], B regs set 0) ----
        if (s + 1 < NS) { LOADB(s + 1, bh1, bl1); LOADT((s + 1) << 5); }
        DOMFMA(0, bh0, bl0);
        if (s + 1 < NS) STORET(1);
        __syncthreads();
        if (s + 1 >= NS) break;
        // ---- step s+1 (reads As[1], B regs set 1) ----
        if (s + 2 < NS) { LOADB(s + 2, bh0, bl0); LOADT((s + 2) << 5); }
        DOMFMA(1, bh1, bl1);
        if (s + 2 < NS) STORET(0);
        __syncthreads();
    }
#undef LOADT
#undef STORET
#undef LOADB
#undef DOMFMA

    // ---- epilogue: scale by deg_out^{-1/2}, store bf16 ----
    // C/D layout: col = lane&15, row = (lane>>4)*4 + reg  [m89/m91-verified]
#pragma unroll
    for (int m = 0; m < 4; ++m) {
#pragma unroll
        for (int i = 0; i < 4; ++i) {
            int row = bm + wr * 64 + m * 16 + l4 * 4 + i;
            if (row < M) {
                int dg = deg[row];
                float sc = rsqrtf((float)(dg > 1 ? dg : 1));
#pragma unroll
                for (int n = 0; n < 4; ++n) {
                    int col = wc * 64 + n * 16 + l15;
                    Hout[(size_t)row * 128 + col] = f2bf(acc[m][n][i] * sc);
                }
            }
        }
    }
}

// ---------------------------------------------------------------------------
// SpMM over buckets: out[n][:] = (sum_j bf16h[bucket[n][j]][:]) * deg^-1/2 + b
// One 64-lane wave per node; lane owns dims {2*lane, 2*lane+1} via uint loads.
// bucket/cnt are single-use streams -> non-temporal, keep L2/LLC for hbuf.
// ---------------------------------------------------------------------------
__global__ __launch_bounds__(256) void spmm_k(const int* __restrict__ cnt,
                                              const int* __restrict__ bucket,
                                              const unsigned int* __restrict__ h32,
                                              const float* __restrict__ bias,
                                              float* __restrict__ out,
                                              int do_relu, int N) {
    const int lane = threadIdx.x & 63;
    const int n = blockIdx.x * 4 + (threadIdx.x >> 6);
    if (n >= N) return;
    const int deg = __builtin_nontemporal_load(&cnt[n]);
    const int e1 = deg < CAP ? deg : CAP;
    const int* __restrict__ bk = bucket + (size_t)n * CAP;
    float a0 = 0.f, a1 = 0.f;
    int e = 0;
    for (; e + 4 <= e1; e += 4) {
        int s0 = __builtin_nontemporal_load(&bk[e + 0]);
        int s1 = __builtin_nontemporal_load(&bk[e + 1]);
        int s2 = __builtin_nontemporal_load(&bk[e + 2]);
        int s3 = __builtin_nontemporal_load(&bk[e + 3]);
        unsigned int v0 = h32[(size_t)s0 * 64 + lane];
        unsigned int v1 = h32[(size_t)s1 * 64 + lane];
        unsigned int v2 = h32[(size_t)s2 * 64 + lane];
        unsigned int v3 = h32[(size_t)s3 * 64 + lane];
        a0 += __uint_as_float(v0 << 16) + __uint_as_float(v1 << 16) +
              __uint_as_float(v2 << 16) + __uint_as_float(v3 << 16);
        a1 += __uint_as_float(v0 & 0xffff0000u) + __uint_as_float(v1 & 0xffff0000u) +
              __uint_as_float(v2 & 0xffff0000u) + __uint_as_float(v3 & 0xffff0000u);
    }
    for (; e < e1; ++e) {
        int sx = __builtin_nontemporal_load(&bk[e]);
        unsigned int v = h32[(size_t)sx * 64 + lane];
        a0 += __uint_as_float(v << 16);
        a1 += __uint_as_float(v & 0xffff0000u);
    }
    float sc = rsqrtf((float)(deg > 1 ? deg : 1));
    float bx = bias[2 * lane], by = bias[2 * lane + 1];
    float r0 = a0 * sc + bx;
    float r1 = a1 * sc + by;
    if (do_relu) { r0 = fmaxf(r0, 0.f); r1 = fmaxf(r1, 0.f); }
    float2 o; o.x = r0; o.y = r1;
    *(float2*)&out[(size_t)n * 128 + 2 * lane] = o;
}

// ---------------------------------------------------------------------------
// launcher
// ---------------------------------------------------------------------------
extern "C" void kernel_launch(void* const* d_in, const int* in_sizes, int n_in,
                              void* d_out, int out_size, void* d_ws, size_t ws_size,
                              hipStream_t stream) {
    const int E = in_sizes[0] / 2;        // 1,600,000
    const int N = in_sizes[1] / IN_DIM;   // 100,000

    const float* W0 = (const float*)d_in[6];
    const float* b0 = (const float*)d_in[7];
    const float* W1 = (const float*)d_in[8];
    const float* b1 = (const float*)d_in[9];
    float* out = (float*)d_out;

    char* ws = (char*)d_ws;
    size_t off = 0;
    auto alloc = [&](size_t bytes) -> void* {
        void* p = ws + off;
        off += (bytes + 255) & ~(size_t)255;
        return p;
    };
    const int B = (N + RANGE - 1) >> RSH;               // 196 bins

    unsigned short* hbuf = (unsigned short*)alloc((size_t)N * HID * 2);  // 25.6MB
    float* x1    = (float*)alloc((size_t)N * HID * 4);                   // 51.2MB
    int* bucket  = (int*)alloc((size_t)N * CAP * 4);                     // 19.2MB
    int* counts  = (int*)alloc((size_t)2 * N * 4);       // deg_out | cnt (no memset needed)
    int* binCnt  = (int*)alloc(2 * MAXB * 4);            // binCntD | binCntS
    unsigned int*   binBufD = (unsigned int*)alloc((size_t)B * CAPB * 4);    // 8.0MB
    unsigned short* binBufS = (unsigned short*)alloc((size_t)B * CAPB * 2);  // 4.0MB
    unsigned short* W0hiT = (unsigned short*)alloc((size_t)IN_DIM * HID * 2);
    unsigned short* W0loT = (unsigned short*)alloc((size_t)IN_DIM * HID * 2);
    unsigned short* W1hiT = (unsigned short*)alloc((size_t)HID * HID * 2);
    unsigned short* W1loT = (unsigned short*)alloc((size_t)HID * HID * 2);
    int* modes   = (int*)alloc(256);

    int* deg_out = counts;
    int* cnt     = counts + N;
    int* binCntD = binCnt;
    int* binCntS = binCnt + MAXB;

    const int gemm_blocks = (N + 127) / 128;
    const int spmm_blocks = (N + 3) / 4;
    const int bin_blocks  = (E + CHUNK - 1) / CHUNK;

    // one detect launch for all three graphs; one weight-prep for the session
    detect3_k<<<3, 256, 0, stream>>>((const int*)d_in[0], (const int*)d_in[2],
                                     (const int*)d_in[4], 2048, modes);
    prep_w_k<<<192, 256, 0, stream>>>(W0, W1, W0hiT, W0loT, W1hiT, W1loT);

    for (int g = 0; g < 3; ++g) {
        const int* e32 = (const int*)d_in[g * 2];
        const float* X = (const float*)d_in[g * 2 + 1];
        float* zout = out + (size_t)g * N * HID;
        const int K1 = in_sizes[g * 2 + 1] / N;  // 256

        hipMemsetAsync(binCnt, 0, 2 * MAXB * 4, stream);
        bin_k<<<bin_blocks, 256, 0, stream>>>(e32, E, modes + g,
                                              binCntD, binCntS, binBufD, binBufS, B);
        build_k<<<2 * B, 256, 0, stream>>>(binCntD, binCntS, binBufD, binBufS,
                                           bucket, cnt, deg_out, B, N);

        // layer 1
        gemm_v3_k<<<gemm_blocks, 256, 0, stream>>>(X, W0hiT, W0loT, deg_out, hbuf, N, K1);
        spmm_k<<<spmm_blocks, 256, 0, stream>>>(cnt, bucket, (const unsigned int*)hbuf, b0, x1, 1, N);

        // layer 2
        gemm_v3_k<<<gemm_blocks, 256, 0, stream>>>(x1, W1hiT, W1loT, deg_out, hbuf, N, HID);
        spmm_k<<<spmm_blocks, 256, 0, stream>>>(cnt, bucket, (const unsigned int*)hbuf, b1, zout, 0, N);
    }
}

// Round 6
// 835.563 us; speedup vs baseline: 1.3557x; 1.3557x over previous
//
#include <hip/hip_runtime.h>

#define IN_DIM 256
#define HID 128
#define CAP 48        // bucket capacity per node; P(Poisson(16) >= 48) ~ 1e-30
#define RANGE 512     // nodes per bin (dst>>9); LDS adjacency 512*48*4 = 96KB
#define RSH 9
#define MAXB 256      // max bins supported (N <= 131072; also s fits 17 bits)
#define CAPB 10240    // per-bin edge capacity (~8163 avg, 25% slack)
#define CHUNK 4096    // edges per bin_k workgroup (256 thr * 16)

using short8 = __attribute__((ext_vector_type(8))) short;
using f32x4  = __attribute__((ext_vector_type(4))) float;

// ---------------------------------------------------------------------------
// bf16 helpers (RNE round, bit-level)
// ---------------------------------------------------------------------------
__device__ __forceinline__ unsigned short f2bf(float x) {
    unsigned int u = __float_as_uint(x);
    u += 0x7fffu + ((u >> 16) & 1u);
    return (unsigned short)(u >> 16);
}
__device__ __forceinline__ float bf2f(unsigned short b) {
    return __uint_as_float((unsigned int)b << 16);
}
__device__ __forceinline__ float bfLO(unsigned int u) { return __uint_as_float(u << 16); }
__device__ __forceinline__ float bfHI(unsigned int u) { return __uint_as_float(u & 0xffff0000u); }

// ---------------------------------------------------------------------------
// int64-vs-int32 edge storage detect for all 3 graphs in one launch
// ---------------------------------------------------------------------------
__global__ void detect3_k(const int* __restrict__ a, const int* __restrict__ b,
                          const int* __restrict__ c, int n_check,
                          int* __restrict__ modes) {
    const int* e = (blockIdx.x == 0) ? a : (blockIdx.x == 1) ? b : c;
    __shared__ int any_nz;
    if (threadIdx.x == 0) any_nz = 0;
    __syncthreads();
    for (int i = threadIdx.x; i < n_check; i += blockDim.x) {
        if (e[2 * i + 1] != 0) atomicOr(&any_nz, 1);
    }
    __syncthreads();
    if (threadIdx.x == 0) modes[blockIdx.x] = any_nz ? 0 : 1;
}

// ---------------------------------------------------------------------------
// One-time weight prep: W[K][128] fp32 -> transposed bf16 hi/lo planes
// W*T[col][k].
// ---------------------------------------------------------------------------
__global__ __launch_bounds__(256) void prep_w_k(const float* __restrict__ W0,
                                                const float* __restrict__ W1,
                                                unsigned short* __restrict__ W0hiT,
                                                unsigned short* __restrict__ W0loT,
                                                unsigned short* __restrict__ W1hiT,
                                                unsigned short* __restrict__ W1loT) {
    int gid = blockIdx.x * 256 + threadIdx.x;
    if (gid < IN_DIM * HID) {
        int k = gid >> 7, c = gid & 127;
        float v = W0[gid];
        unsigned short h = f2bf(v), l = f2bf(v - bf2f(h));
        W0hiT[(size_t)c * IN_DIM + k] = h;
        W0loT[(size_t)c * IN_DIM + k] = l;
    } else if (gid < IN_DIM * HID + HID * HID) {
        int g2 = gid - IN_DIM * HID;
        int k = g2 >> 7, c = g2 & 127;
        float v = W1[g2];
        unsigned short h = f2bf(v), l = f2bf(v - bf2f(h));
        W1hiT[(size_t)c * HID + k] = h;
        W1loT[(size_t)c * HID + k] = l;
    }
}

// ---------------------------------------------------------------------------
// Pass 1: radix-bin edges by dst>>RSH (payload pack: s | d_local<<17) and by
// src>>RSH (payload: s_local ushort). Replaces 3.2M global atomics + 1.6M
// random 4B stores with LDS histograms + ~150K global atomics + clustered
// appends (R3: killed the 143us preprocess fabric-scatter bottleneck).
// ---------------------------------------------------------------------------
__global__ __launch_bounds__(256) void bin_k(const int* __restrict__ e32, int E,
                                             const int* __restrict__ mode_p,
                                             int* __restrict__ binCntD,
                                             int* __restrict__ binCntS,
                                             unsigned int* __restrict__ binBufD,
                                             unsigned short* __restrict__ binBufS,
                                             int B) {
    __shared__ int hcD[MAXB], hcS[MAXB];
    __shared__ int baseD[MAXB], baseS[MAXB];
    const int t = threadIdx.x;
    for (int i = t; i < B; i += 256) { hcD[i] = 0; hcS[i] = 0; }
    __syncthreads();

    int s[16], d[16];
    const long long e0 = (long long)blockIdx.x * CHUNK;
    const int mode = *mode_p;

    if (mode) {  // int64 storage, values fit in low word
        const long long* __restrict__ s64 = (const long long*)e32;
        const long long* __restrict__ d64 = s64 + E;
#pragma unroll
        for (int j = 0; j < 16; ++j) {
            long long idx = e0 + j * 256 + t;
            if (idx < E) { s[j] = (int)s64[idx]; d[j] = (int)d64[idx]; }
            else         { s[j] = -1; d[j] = -1; }
        }
    } else {     // int32 storage
        const int* __restrict__ s32 = e32;
        const int* __restrict__ d32 = e32 + E;
#pragma unroll
        for (int j = 0; j < 16; ++j) {
            long long idx = e0 + j * 256 + t;
            if (idx < E) { s[j] = s32[idx]; d[j] = d32[idx]; }
            else         { s[j] = -1; d[j] = -1; }
        }
    }

    // count
#pragma unroll
    for (int j = 0; j < 16; ++j) {
        if (d[j] >= 0) {
            atomicAdd(&hcD[d[j] >> RSH], 1);
            atomicAdd(&hcS[s[j] >> RSH], 1);
        }
    }
    __syncthreads();

    // reserve global space per bin; reset hc for reuse as local offsets
    for (int i = t; i < B; i += 256) {
        int c = hcD[i];
        baseD[i] = c ? atomicAdd(&binCntD[i], c) : 0;
        hcD[i] = 0;
        c = hcS[i];
        baseS[i] = c ? atomicAdd(&binCntS[i], c) : 0;
        hcS[i] = 0;
    }
    __syncthreads();

    // place
#pragma unroll
    for (int j = 0; j < 16; ++j) {
        if (d[j] >= 0) {
            int bD = d[j] >> RSH;
            int p = atomicAdd(&hcD[bD], 1) + baseD[bD];
            if (p < CAPB)
                binBufD[(size_t)bD * CAPB + p] =
                    (unsigned int)s[j] | ((unsigned int)(d[j] & (RANGE - 1)) << 17);
            int bS = s[j] >> RSH;
            int q = atomicAdd(&hcS[bS], 1) + baseS[bS];
            if (q < CAPB)
                binBufS[(size_t)bS * CAPB + q] = (unsigned short)(s[j] & (RANGE - 1));
        }
    }
}

// ---------------------------------------------------------------------------
// Pass 2: blocks [0,B) build dst-adjacency in LDS (atomics at LDS speed),
// then stream bucket rows + true cnt out coalesced. Blocks [B,2B) histogram
// src-bins in LDS and write deg_out coalesced.
// Writes cnt/deg_out for ALL nodes -> no global memset needed for them.
// ---------------------------------------------------------------------------
__global__ __launch_bounds__(256) void build_k(const int* __restrict__ binCntD,
                                               const int* __restrict__ binCntS,
                                               const unsigned int* __restrict__ binBufD,
                                               const unsigned short* __restrict__ binBufS,
                                               int* __restrict__ bucket,
                                               int* __restrict__ cnt,
                                               int* __restrict__ deg_out,
                                               int B, int N) {
    __shared__ int lcnt[RANGE];
    __shared__ int lbuf[RANGE * CAP];   // 96KB
    const int t = threadIdx.x;

    if ((int)blockIdx.x < B) {
        const int bin = blockIdx.x;
        for (int i = t; i < RANGE; i += 256) lcnt[i] = 0;
        __syncthreads();
        const int nE = min(binCntD[bin], CAPB);
        const unsigned int* __restrict__ src = binBufD + (size_t)bin * CAPB;
        for (int i = t; i < nE; i += 256) {
            unsigned int v = src[i];
            int dl = v >> 17;
            int p = atomicAdd(&lcnt[dl], 1);
            if (p < CAP) lbuf[dl * CAP + p] = (int)(v & 0x1FFFFu);
        }
        __syncthreads();
        const int node0 = bin * RANGE;
        const int nn = min(RANGE, N - node0);
        for (int i = t; i < nn; i += 256) cnt[node0 + i] = lcnt[i];
        for (int i = t; i < nn * CAP; i += 256)
            bucket[(size_t)node0 * CAP + i] = lbuf[i];
    } else {
        const int bin = blockIdx.x - B;
        for (int i = t; i < RANGE; i += 256) lcnt[i] = 0;
        __syncthreads();
        const int nE = min(binCntS[bin], CAPB);
        const unsigned short* __restrict__ src = binBufS + (size_t)bin * CAPB;
        for (int i = t; i < nE; i += 256) atomicAdd(&lcnt[src[i]], 1);
        __syncthreads();
        const int node0 = bin * RANGE;
        const int nn = min(RANGE, N - node0);
        for (int i = t; i < nn; i += 256) deg_out[node0 + i] = lcnt[i];
    }
}

// ---------------------------------------------------------------------------
// bf16-split MFMA GEMM v4:
//   Hout[row][0:128] = bf16( (X[row][0:K] @ W[K][128]) * clip(deg,1)^-1/2 )
// R5 lesson: B-register prefetch -> VGPR 172 -> occupancy cliff (8.9%).
// v4 = v2's low-VGPR structure (B fragments straight from L2-hot transposed
// global planes, no reg prefetch) at HALF the block: BM=64, 2-wave/128-thread
// blocks, 16KB LDS -> 1563 independent barrier groups, ~6 blocks/CU, so
// block-level TLP hides the X-HBM and B-L2 latency the barrier serializes.
// MFMA order identical to v2/v3 -> bitwise-same results.
// ---------------------------------------------------------------------------
__global__ __launch_bounds__(128) void gemm_v4_k(const float* __restrict__ X,
                                                 const unsigned short* __restrict__ BhiT,
                                                 const unsigned short* __restrict__ BloT,
                                                 const int* __restrict__ deg,
                                                 unsigned short* __restrict__ Hout,
                                                 int M, int K) {
    __shared__ __align__(16) unsigned short As[2][2][64 * 32];  // [buf][hi/lo], 16KB

    const int tid = threadIdx.x;
    const int lane = tid & 63;
    const int w = tid >> 6;            // 0..1 -> column half of the 128-wide tile
    const int bm = blockIdx.x * 64;
    const int l15 = lane & 15, l4 = lane >> 4;
    const int r0 = tid >> 3;           // 0..15; thread covers rows r0+16i
    const int kq = tid & 7;            // float4 slot within the 32-wide k panel

    f32x4 acc[4][4];
#pragma unroll
    for (int m = 0; m < 4; ++m)
#pragma unroll
        for (int n = 0; n < 4; ++n) acc[m][n] = (f32x4){0.f, 0.f, 0.f, 0.f};

    float4 pf[4];

#define LOADT(k0)                                                              \
    {                                                                          \
        _Pragma("unroll")                                                      \
        for (int i = 0; i < 4; ++i) {                                          \
            int r = r0 + i * 16;                                               \
            pf[i] = make_float4(0.f, 0.f, 0.f, 0.f);                           \
            if (bm + r < M)                                                    \
                pf[i] = *(const float4*)&X[(size_t)(bm + r) * K + (k0) + kq * 4]; \
        }                                                                      \
    }

#define STORET(buf)                                                            \
    {                                                                          \
        _Pragma("unroll")                                                      \
        for (int i = 0; i < 4; ++i) {                                          \
            int r = r0 + i * 16;                                               \
            ushort4 h, l;                                                      \
            h.x = f2bf(pf[i].x); l.x = f2bf(pf[i].x - bf2f(h.x));              \
            h.y = f2bf(pf[i].y); l.y = f2bf(pf[i].y - bf2f(h.y));              \
            h.z = f2bf(pf[i].z); l.z = f2bf(pf[i].z - bf2f(h.z));              \
            h.w = f2bf(pf[i].w); l.w = f2bf(pf[i].w - bf2f(h.w));              \
            *(ushort4*)&As[buf][0][r * 32 + kq * 4] = h;                       \
            *(ushort4*)&As[buf][1][r * 32 + kq * 4] = l;                       \
        }                                                                      \
    }

    LOADT(0);
    STORET(0);
    __syncthreads();

    const int NS = K >> 5;
    for (int s = 0; s < NS; ++s) {
        const int buf = s & 1;
        if (s + 1 < NS) LOADT((s + 1) << 5);

        short8 ah[4], al[4], bh[4], bl[4];
#pragma unroll
        for (int m = 0; m < 4; ++m) {
            int row = m * 16 + l15;
            ah[m] = *(const short8*)&As[buf][0][row * 32 + l4 * 8];
            al[m] = *(const short8*)&As[buf][1][row * 32 + l4 * 8];
        }
        const int kb = (s << 5) + l4 * 8;
#pragma unroll
        for (int n = 0; n < 4; ++n) {
            int col = w * 64 + n * 16 + l15;
            bh[n] = *(const short8*)&BhiT[(size_t)col * K + kb];
            bl[n] = *(const short8*)&BloT[(size_t)col * K + kb];
        }

        // hi*hi + lo*hi + hi*lo
#pragma unroll
        for (int m = 0; m < 4; ++m)
#pragma unroll
            for (int n = 0; n < 4; ++n) {
                acc[m][n] = __builtin_amdgcn_mfma_f32_16x16x32_bf16(ah[m], bh[n], acc[m][n], 0, 0, 0);
                acc[m][n] = __builtin_amdgcn_mfma_f32_16x16x32_bf16(al[m], bh[n], acc[m][n], 0, 0, 0);
                acc[m][n] = __builtin_amdgcn_mfma_f32_16x16x32_bf16(ah[m], bl[n], acc[m][n], 0, 0, 0);
            }

        if (s + 1 < NS) STORET(buf ^ 1);
        __syncthreads();
    }
#undef LOADT
#undef STORET

    // ---- epilogue: scale by deg_out^{-1/2}, store bf16 ----
    // C/D layout: col = lane&15, row = (lane>>4)*4 + reg  [m89/m91-verified]
#pragma unroll
    for (int m = 0; m < 4; ++m) {
#pragma unroll
        for (int i = 0; i < 4; ++i) {
            int row = bm + m * 16 + l4 * 4 + i;
            if (row < M) {
                int dg = deg[row];
                float sc = rsqrtf((float)(dg > 1 ? dg : 1));
#pragma unroll
                for (int n = 0; n < 4; ++n) {
                    int col = w * 64 + n * 16 + l15;
                    Hout[(size_t)row * 128 + col] = f2bf(acc[m][n][i] * sc);
                }
            }
        }
    }
}

// ---------------------------------------------------------------------------
// SpMM over buckets: out[n][:] = (sum_j bf16h[bucket[n][j]][:]) * deg^-1/2 + b
// v2: uint2 (8B) per lane, lanes 0-31 take even edges / 32-63 odd edges ->
// each load instr covers TWO 256B rows; 8 rows in flight per iteration
// (R5: 4B/lane x4-unroll was MLP-starved at 2.7 TB/s). Final shfl_xor(32)
// folds the halves (bucket order is already nondeterministic -> summation
// order change is within tolerance).
// ---------------------------------------------------------------------------
__global__ __launch_bounds__(256) void spmm_k(const int* __restrict__ cnt,
                                              const int* __restrict__ bucket,
                                              const uint2* __restrict__ h64,
                                              const float* __restrict__ bias,
                                              float* __restrict__ out,
                                              int do_relu, int N) {
    const int lane = threadIdx.x & 63;
    const int half = lane >> 5;        // 0: edges e+0,2,..  1: edges e+1,3,..
    const int j = lane & 31;           // uint2 index in row (dims 4j..4j+3)
    const int n = blockIdx.x * 4 + (threadIdx.x >> 6);
    if (n >= N) return;
    const int deg = cnt[n];
    const int e1 = deg < CAP ? deg : CAP;
    const int* __restrict__ bk = bucket + (size_t)n * CAP;
    float a0 = 0.f, a1 = 0.f, a2 = 0.f, a3 = 0.f;
    int e = 0;
    for (; e + 8 <= e1; e += 8) {
        int s0 = bk[e + 0 + half], s1 = bk[e + 2 + half];
        int s2 = bk[e + 4 + half], s3 = bk[e + 6 + half];
        uint2 v0 = h64[(size_t)s0 * 32 + j];
        uint2 v1 = h64[(size_t)s1 * 32 + j];
        uint2 v2 = h64[(size_t)s2 * 32 + j];
        uint2 v3 = h64[(size_t)s3 * 32 + j];
        a0 += bfLO(v0.x) + bfLO(v1.x) + bfLO(v2.x) + bfLO(v3.x);
        a1 += bfHI(v0.x) + bfHI(v1.x) + bfHI(v2.x) + bfHI(v3.x);
        a2 += bfLO(v0.y) + bfLO(v1.y) + bfLO(v2.y) + bfLO(v3.y);
        a3 += bfHI(v0.y) + bfHI(v1.y) + bfHI(v2.y) + bfHI(v3.y);
    }
    for (; e + 2 <= e1; e += 2) {
        int s = bk[e + half];
        uint2 v = h64[(size_t)s * 32 + j];
        a0 += bfLO(v.x); a1 += bfHI(v.x); a2 += bfLO(v.y); a3 += bfHI(v.y);
    }
    if (e < e1 && half == 0) {  // odd tail: single row, lanes 0-31 only
        int s = bk[e];
        uint2 v = h64[(size_t)s * 32 + j];
        a0 += bfLO(v.x); a1 += bfHI(v.x); a2 += bfLO(v.y); a3 += bfHI(v.y);
    }
    // fold the two half-wave partial sums
    a0 += __shfl_xor(a0, 32);
    a1 += __shfl_xor(a1, 32);
    a2 += __shfl_xor(a2, 32);
    a3 += __shfl_xor(a3, 32);

    if (half == 0) {
        float sc = rsqrtf((float)(deg > 1 ? deg : 1));
        const float4 bv = *(const float4*)&bias[4 * j];
        float r0 = a0 * sc + bv.x;
        float r1 = a1 * sc + bv.y;
        float r2 = a2 * sc + bv.z;
        float r3 = a3 * sc + bv.w;
        if (do_relu) {
            r0 = fmaxf(r0, 0.f); r1 = fmaxf(r1, 0.f);
            r2 = fmaxf(r2, 0.f); r3 = fmaxf(r3, 0.f);
        }
        float4 o; o.x = r0; o.y = r1; o.z = r2; o.w = r3;
        *(float4*)&out[(size_t)n * 128 + 4 * j] = o;
    }
}

// ---------------------------------------------------------------------------
// launcher
// ---------------------------------------------------------------------------
extern "C" void kernel_launch(void* const* d_in, const int* in_sizes, int n_in,
                              void* d_out, int out_size, void* d_ws, size_t ws_size,
                              hipStream_t stream) {
    const int E = in_sizes[0] / 2;        // 1,600,000
    const int N = in_sizes[1] / IN_DIM;   // 100,000

    const float* W0 = (const float*)d_in[6];
    const float* b0 = (const float*)d_in[7];
    const float* W1 = (const float*)d_in[8];
    const float* b1 = (const float*)d_in[9];
    float* out = (float*)d_out;

    char* ws = (char*)d_ws;
    size_t off = 0;
    auto alloc = [&](size_t bytes) -> void* {
        void* p = ws + off;
        off += (bytes + 255) & ~(size_t)255;
        return p;
    };
    const int B = (N + RANGE - 1) >> RSH;               // 196 bins

    unsigned short* hbuf = (unsigned short*)alloc((size_t)N * HID * 2);  // 25.6MB
    float* x1    = (float*)alloc((size_t)N * HID * 4);                   // 51.2MB
    int* bucket  = (int*)alloc((size_t)N * CAP * 4);                     // 19.2MB
    int* counts  = (int*)alloc((size_t)2 * N * 4);       // deg_out | cnt (no memset needed)
    int* binCnt  = (int*)alloc(2 * MAXB * 4);            // binCntD | binCntS
    unsigned int*   binBufD = (unsigned int*)alloc((size_t)B * CAPB * 4);    // 8.0MB
    unsigned short* binBufS = (unsigned short*)alloc((size_t)B * CAPB * 2);  // 4.0MB
    unsigned short* W0hiT = (unsigned short*)alloc((size_t)IN_DIM * HID * 2);
    unsigned short* W0loT = (unsigned short*)alloc((size_t)IN_DIM * HID * 2);
    unsigned short* W1hiT = (unsigned short*)alloc((size_t)HID * HID * 2);
    unsigned short* W1loT = (unsigned short*)alloc((size_t)HID * HID * 2);
    int* modes   = (int*)alloc(256);

    int* deg_out = counts;
    int* cnt     = counts + N;
    int* binCntD = binCnt;
    int* binCntS = binCnt + MAXB;

    const int gemm_blocks = (N + 63) / 64;
    const int spmm_blocks = (N + 3) / 4;
    const int bin_blocks  = (E + CHUNK - 1) / CHUNK;

    // one detect launch for all three graphs; one weight-prep for the session
    detect3_k<<<3, 256, 0, stream>>>((const int*)d_in[0], (const int*)d_in[2],
                                     (const int*)d_in[4], 2048, modes);
    prep_w_k<<<192, 256, 0, stream>>>(W0, W1, W0hiT, W0loT, W1hiT, W1loT);

    for (int g = 0; g < 3; ++g) {
        const int* e32 = (const int*)d_in[g * 2];
        const float* X = (const float*)d_in[g * 2 + 1];
        float* zout = out + (size_t)g * N * HID;
        const int K1 = in_sizes[g * 2 + 1] / N;  // 256

        hipMemsetAsync(binCnt, 0, 2 * MAXB * 4, stream);
        bin_k<<<bin_blocks, 256, 0, stream>>>(e32, E, modes + g,
                                              binCntD, binCntS, binBufD, binBufS, B);
        build_k<<<2 * B, 256, 0, stream>>>(binCntD, binCntS, binBufD, binBufS,
                                           bucket, cnt, deg_out, B, N);

        // layer 1
        gemm_v4_k<<<gemm_blocks, 128, 0, stream>>>(X, W0hiT, W0loT, deg_out, hbuf, N, K1);
        spmm_k<<<spmm_blocks, 256, 0, stream>>>(cnt, bucket, (const uint2*)hbuf, b0, x1, 1, N);

        // layer 2
        gemm_v4_k<<<gemm_blocks, 128, 0, stream>>>(x1, W1hiT, W1loT, deg_out, hbuf, N, HID);
        spmm_k<<<spmm_blocks, 256, 0, stream>>>(cnt, bucket, (const uint2*)hbuf, b1, zout, 0, N);
    }
}